// Round 1
// baseline (32692.130 us; speedup 1.0000x reference)
//
#include <hip/hip_runtime.h>
#include <math.h>

// ESN recurrence: x_t = tanh(u_t @ w_in^T + w_bias + W @ h_{t-1}), h_0 = 0.
// B=8 batches, T=4096 steps, D_RES=1024, D_IN=64, all fp32.
//
// Design: 256 WGs (= 8 batches x 32 row-chunks), 256 threads each.
// Each WG holds a 32x1024 slab of W in registers (128 VGPR/thread) plus its
// w_in slab (8 regs) -- W is never re-read after the prologue. Per step:
// register-resident matvec with h broadcast from LDS, butterfly reduce,
// tanh, publish 32 h values to a global double buffer, per-batch 32-WG
// barrier (one-shot per-(t,b) counters, agent-scope release/acquire), then
// restage h into LDS. blockIdx%8 = batch keeps a batch's WGs on one XCD
// (perf heuristic only; correctness uses agent-scope fences).

#define NB        8
#define T_STEPS   4096
#define DRES      1024
#define DIN       64
#define CHUNKS    32      // WGs per batch
#define NTHREADS  256

// ws layout: [hbuf: 2*NB*DRES floats = 64 KB][ctr: T_STEPS*NB uints = 128 KB]
#define HBUF_FLOATS (2 * NB * DRES)
#define CTR_OFFSET  (HBUF_FLOATS * sizeof(float))
#define WS_BYTES    (CTR_OFFSET + (size_t)T_STEPS * NB * sizeof(unsigned int))

__launch_bounds__(NTHREADS, 1)
__global__ void esn_kernel(const float* __restrict__ u,      // [NB][T][DIN]
                           const float* __restrict__ w_in,   // [DRES][DIN]
                           const float* __restrict__ w,      // [DRES][DRES]
                           const float* __restrict__ w_bias, // [DRES]
                           float* __restrict__ out,          // [NB][T][DRES]
                           float* __restrict__ hbuf,         // [2][NB][DRES]
                           unsigned int* __restrict__ ctr)   // [T_STEPS][NB]
{
    const int tid   = threadIdx.x;
    const int b     = blockIdx.x & (NB - 1);   // batch -> XCD affinity
    const int chunk = blockIdx.x >> 3;         // 0..31 row-chunk
    const int rg    = tid >> 5;                // 0..7 row-group (4 rows each)
    const int mc    = tid & 31;                // 0..31 m-lane
    const int row0  = chunk * 32 + rg * 4;     // first of this thread's 4 rows

    __shared__ float h_lds[DRES];

    // ---- prologue: weights into registers ----
    float wreg[4][32];                         // wreg[i][j] = W[row0+i][mc+32j]
    #pragma unroll
    for (int i = 0; i < 4; ++i) {
        const float* wr = w + (size_t)(row0 + i) * DRES + mc;
        #pragma unroll
        for (int j = 0; j < 32; ++j)
            wreg[i][j] = wr[32 * j];
    }
    float win0[4], win1[4];                    // w_in[row][2mc], w_in[row][2mc+1]
    #pragma unroll
    for (int i = 0; i < 4; ++i) {
        win0[i] = w_in[(row0 + i) * DIN + 2 * mc];
        win1[i] = w_in[(row0 + i) * DIN + 2 * mc + 1];
    }
    float bias[4];
    #pragma unroll
    for (int i = 0; i < 4; ++i)
        bias[i] = w_bias[row0 + i];

    // h_0 = 0
    #pragma unroll
    for (int k = tid; k < DRES; k += NTHREADS)
        h_lds[k] = 0.0f;
    __syncthreads();

    const float* ub = u + (size_t)b * T_STEPS * DIN;
    float2 ucur = *(const float2*)(ub + 2 * mc);   // u_0 slice

    float* hb[2] = { hbuf, hbuf + NB * DRES };

    #pragma unroll 1
    for (int t = 0; t < T_STEPS; ++t) {
        // prefetch next step's u slice (hidden behind compute+sync)
        const int tn = (t + 1 < T_STEPS) ? (t + 1) : t;
        const float2 unext = *(const float2*)(ub + (size_t)tn * DIN + 2 * mc);

        // partials: input projection + recurrent matvec (W in regs, h bcast from LDS)
        float acc[4];
        #pragma unroll
        for (int i = 0; i < 4; ++i)
            acc[i] = fmaf(win0[i], ucur.x, win1[i] * ucur.y);
        #pragma unroll
        for (int j = 0; j < 32; ++j) {
            const float hv = h_lds[mc + 32 * j];
            #pragma unroll
            for (int i = 0; i < 4; ++i)
                acc[i] = fmaf(wreg[i][j], hv, acc[i]);
        }

        // butterfly reduce across the 32 m-lanes (stays within 32-lane halves)
        #pragma unroll
        for (int d = 1; d < 32; d <<= 1) {
            #pragma unroll
            for (int i = 0; i < 4; ++i)
                acc[i] += __shfl_xor(acc[i], d, 64);
        }

        // tanh on all lanes (uniform, no divergence); writers store
        float x[4];
        #pragma unroll
        for (int i = 0; i < 4; ++i) {
            const float z = acc[i] + bias[i];
            const float e = __expf(2.0f * z);
            x[i] = 1.0f - 2.0f / (e + 1.0f);
        }
        if (mc == 0) {
            const float4 v = make_float4(x[0], x[1], x[2], x[3]);
            *(float4*)(out + ((size_t)b * T_STEPS + t) * DRES + row0) = v;
            *(float4*)(hb[t & 1] + b * DRES + row0) = v;
        }
        ucur = unext;

        if (t + 1 == T_STEPS) break;

        // ---- per-batch barrier across the 32 chunk-WGs ----
        __syncthreads();   // drains vmcnt: all WG stores have reached L2
        if (tid == 0) {
            unsigned int* c = ctr + (size_t)t * NB + b;
            __hip_atomic_fetch_add(c, 1u, __ATOMIC_RELEASE, __HIP_MEMORY_SCOPE_AGENT);
            while (__hip_atomic_load(c, __ATOMIC_RELAXED, __HIP_MEMORY_SCOPE_AGENT) < CHUNKS) {
                __builtin_amdgcn_s_sleep(1);
            }
            __builtin_amdgcn_fence(__ATOMIC_ACQUIRE, "agent");
        }
        __syncthreads();

        // restage full h_t into LDS (coalesced float4 per thread)
        const float4 hv4 = *(const float4*)(hb[t & 1] + b * DRES + tid * 4);
        *(float4*)(&h_lds[tid * 4]) = hv4;
        __syncthreads();
    }
}

extern "C" void kernel_launch(void* const* d_in, const int* in_sizes, int n_in,
                              void* d_out, int out_size, void* d_ws, size_t ws_size,
                              hipStream_t stream) {
    const float* u      = (const float*)d_in[0];
    const float* w_in   = (const float*)d_in[1];
    const float* w      = (const float*)d_in[2];
    const float* w_bias = (const float*)d_in[3];
    float* out = (float*)d_out;

    float* hbuf = (float*)d_ws;
    unsigned int* ctr = (unsigned int*)((char*)d_ws + CTR_OFFSET);

    // zero the h double-buffer + barrier counters (ws is poisoned each call)
    hipMemsetAsync(d_ws, 0, WS_BYTES, stream);

    esn_kernel<<<NB * CHUNKS, NTHREADS, 0, stream>>>(u, w_in, w, w_bias, out, hbuf, ctr);
}

// Round 2
// 9428.101 us; speedup vs baseline: 3.4675x; 3.4675x over previous
//
#include <hip/hip_runtime.h>
#include <math.h>

// ESN recurrence: x_t = tanh(u_t @ w_in^T + w_bias + W @ h_{t-1}), h_0 = 0.
// B=8, T=4096, D_RES=1024, D_IN=64, fp32.
//
// 256 WGs (= 8 batches x 32 row-chunks) x 256 threads. Each WG holds a
// 32x1024 W slab in registers. Per step: register matvec (h broadcast from
// LDS), butterfly reduce, tanh, publish 32 h values + per-batch barrier.
//
// R2 change vs R1: the barrier used RELEASE/ACQUIRE at agent scope, which on
// gfx950 emits buffer_wbl2 (L2 writeback) / buffer_inv (cache invalidate)
// EVERY STEP -> ~7.6 us/step of cache maintenance (evidence: WRITE_SIZE
// 295 MB = out 134 MB + 134 MB of per-step hbuf L2 writebacks; VALUBusy 5%).
// Now: relaxed-only protocol. Data + tags move via sc0/sc1 cache-bypassing
// relaxed agent atomics (write-through, always-fresh reads); ordering via
// per-wave s_waitcnt vmcnt(0) + __syncthreads before the arrival add.
// No release/acquire fences -> no wbl2/inv in the loop.

#define NB        8
#define T_STEPS   4096
#define DRES      1024
#define DIN       64
#define CHUNKS    32      // WGs per batch
#define NTHREADS  256

// ws layout: [hbuf: 2*NB*DRES floats = 64 KB][ctr: T_STEPS*NB uints = 128 KB]
#define HBUF_FLOATS (2 * NB * DRES)
#define CTR_OFFSET  (HBUF_FLOATS * sizeof(float))
#define CTR_BYTES   ((size_t)T_STEPS * NB * sizeof(unsigned int))

__launch_bounds__(NTHREADS, 1)
__global__ void esn_kernel(const float* __restrict__ u,      // [NB][T][DIN]
                           const float* __restrict__ w_in,   // [DRES][DIN]
                           const float* __restrict__ w,      // [DRES][DRES]
                           const float* __restrict__ w_bias, // [DRES]
                           float* __restrict__ out,          // [NB][T][DRES]
                           float* __restrict__ hbuf,         // [2][NB][DRES]
                           unsigned int* __restrict__ ctr)   // [T_STEPS][NB]
{
    const int tid   = threadIdx.x;
    const int b     = blockIdx.x & (NB - 1);   // batch -> XCD affinity heuristic
    const int chunk = blockIdx.x >> 3;         // 0..31 row-chunk
    const int rg    = tid >> 5;                // 0..7 row-group (4 rows each)
    const int mc    = tid & 31;                // 0..31 k-lane
    const int row0  = chunk * 32 + rg * 4;     // first of this thread's 4 rows

    __shared__ float h_lds[DRES];

    // ---- prologue: weights into registers ----
    float wreg[4][32];                         // wreg[i][j] = W[row0+i][mc+32j]
    #pragma unroll
    for (int i = 0; i < 4; ++i) {
        const float* wr = w + (size_t)(row0 + i) * DRES + mc;
        #pragma unroll
        for (int j = 0; j < 32; ++j)
            wreg[i][j] = wr[32 * j];
    }
    float win0[4], win1[4];                    // w_in[row][2mc], w_in[row][2mc+1]
    #pragma unroll
    for (int i = 0; i < 4; ++i) {
        win0[i] = w_in[(row0 + i) * DIN + 2 * mc];
        win1[i] = w_in[(row0 + i) * DIN + 2 * mc + 1];
    }
    float bias[4];
    #pragma unroll
    for (int i = 0; i < 4; ++i)
        bias[i] = w_bias[row0 + i];

    // h_0 = 0
    #pragma unroll
    for (int k = tid; k < DRES; k += NTHREADS)
        h_lds[k] = 0.0f;
    __syncthreads();

    const float* ub = u + (size_t)b * T_STEPS * DIN;
    float2 ucur = *(const float2*)(ub + 2 * mc);   // u_0 slice

    #pragma unroll 1
    for (int t = 0; t < T_STEPS; ++t) {
        // prefetch next step's u slice (hidden behind compute+sync)
        const int tn = (t + 1 < T_STEPS) ? (t + 1) : t;
        const float2 unext = *(const float2*)(ub + (size_t)tn * DIN + 2 * mc);

        // input projection + recurrent matvec (W in regs, h bcast from LDS)
        float acc[4];
        #pragma unroll
        for (int i = 0; i < 4; ++i)
            acc[i] = fmaf(win0[i], ucur.x, win1[i] * ucur.y);
        #pragma unroll
        for (int j = 0; j < 32; ++j) {
            const float hv = h_lds[mc + 32 * j];
            #pragma unroll
            for (int i = 0; i < 4; ++i)
                acc[i] = fmaf(wreg[i][j], hv, acc[i]);
        }

        // butterfly reduce across the 32 k-lanes (stays within 32-lane halves)
        #pragma unroll
        for (int d = 1; d < 32; d <<= 1) {
            #pragma unroll
            for (int i = 0; i < 4; ++i)
                acc[i] += __shfl_xor(acc[i], d, 64);
        }

        // tanh on all lanes (uniform, no divergence)
        float x[4];
        #pragma unroll
        for (int i = 0; i < 4; ++i) {
            const float z = acc[i] + bias[i];
            const float e = __expf(2.0f * z);
            x[i] = 1.0f - 2.0f / (e + 1.0f);
        }

        // output store: normal cached path (nobody reads it; L2 writes back lazily)
        if (mc == 0) {
            *(float4*)(out + ((size_t)b * T_STEPS + t) * DRES + row0) =
                make_float4(x[0], x[1], x[2], x[3]);
        }

        // publish h values: write-through relaxed agent stores (no wbl2 needed)
        float* hb = hbuf + (t & 1) * NB * DRES + b * DRES;
        if (mc < 4) {
            const float v = (mc & 2) ? ((mc & 1) ? x[3] : x[2])
                                     : ((mc & 1) ? x[1] : x[0]);
            __hip_atomic_store(hb + row0 + mc, v,
                               __ATOMIC_RELAXED, __HIP_MEMORY_SCOPE_AGENT);
        }
        ucur = unext;

        if (t + 1 == T_STEPS) break;

        // ---- per-batch barrier across the 32 chunk-WGs (relaxed-only) ----
        __builtin_amdgcn_s_waitcnt(0);   // this wave's stores acked at coherence pt
        __syncthreads();                 // all waves' stores drained
        if (tid == 0) {
            unsigned int* c = ctr + (size_t)t * NB + b;
            __hip_atomic_fetch_add(c, 1u, __ATOMIC_RELAXED, __HIP_MEMORY_SCOPE_AGENT);
            while (__hip_atomic_load(c, __ATOMIC_RELAXED, __HIP_MEMORY_SCOPE_AGENT) < CHUNKS) {
                __builtin_amdgcn_s_sleep(1);
            }
        }
        __syncthreads();

        // restage h_t into LDS via cache-bypassing relaxed agent loads
        float hv[4];
        #pragma unroll
        for (int i = 0; i < 4; ++i)
            hv[i] = __hip_atomic_load(hb + tid + 256 * i,
                                      __ATOMIC_RELAXED, __HIP_MEMORY_SCOPE_AGENT);
        #pragma unroll
        for (int i = 0; i < 4; ++i)
            h_lds[tid + 256 * i] = hv[i];
        __syncthreads();
    }
}

extern "C" void kernel_launch(void* const* d_in, const int* in_sizes, int n_in,
                              void* d_out, int out_size, void* d_ws, size_t ws_size,
                              hipStream_t stream) {
    const float* u      = (const float*)d_in[0];
    const float* w_in   = (const float*)d_in[1];
    const float* w      = (const float*)d_in[2];
    const float* w_bias = (const float*)d_in[3];
    float* out = (float*)d_out;

    float* hbuf = (float*)d_ws;
    unsigned int* ctr = (unsigned int*)((char*)d_ws + CTR_OFFSET);

    // barrier counters must start at zero (ws is re-poisoned before every call)
    hipMemsetAsync(ctr, 0, CTR_BYTES, stream);

    esn_kernel<<<NB * CHUNKS, NTHREADS, 0, stream>>>(u, w_in, w, w_bias, out, hbuf, ctr);
}